// Round 1
// baseline (232.912 us; speedup 1.0000x reference)
//
#include <hip/hip_runtime.h>
#include <stdint.h>

// ---------------------------------------------------------------------------
// WeightGenerator_V4: fused implementation.
// K1: gate conv(1x1,256->128)+BN+StarReLU, grouped 3x3 (256->64), dw3x3, dw5x5,
//     multiply -> xc (bf16, [b][h][w][128]); also converts w_lin to bf16.
// K2: per 8x8 patch of y: regenerate W(256x256) from w_lin@xc via MFMA into LDS
//     (64-channel chunks), then out_patch(256x64) = W @ Y_patch via MFMA.
//     wdec (134 MB) is NEVER written to HBM.
// ---------------------------------------------------------------------------

typedef __attribute__((ext_vector_type(8))) short short8;
typedef __attribute__((ext_vector_type(4))) float f32x4;

#define BN_EPS 1e-5f

__device__ __forceinline__ unsigned short f2bf(float f) {
  unsigned u = __float_as_uint(f);
  return (unsigned short)((u + 0x8000u) >> 16);   // round-half-up, fine at this tolerance
}
__device__ __forceinline__ unsigned pk2bf(float a, float b) {
  unsigned ua = __float_as_uint(a), ub = __float_as_uint(b);
  return ((ua + 0x8000u) >> 16) | ((ub + 0x8000u) & 0xFFFF0000u);
}
__device__ __forceinline__ float bf2f(short s) {
  return __uint_as_float(((unsigned)(unsigned short)s) << 16);
}

// =====================  K1: feature/gate branch -> xc  =====================
// grid 128 blocks (2 batches x 8x8 tiles of 2x2 pixels), 256 threads.
__global__ __launch_bounds__(256) void k1_features(
    const float* __restrict__ x, const float* __restrict__ w_cr, const float* __restrict__ b_cr,
    const float* __restrict__ w_dw3, const float* __restrict__ b_dw3,
    const float* __restrict__ w_dw7, const float* __restrict__ b_dw7,
    const float* __restrict__ w_gate, const float* __restrict__ b_gate,
    const float* __restrict__ bn_gamma, const float* __restrict__ bn_beta,
    const float* __restrict__ bn_mean, const float* __restrict__ bn_var,
    const float* __restrict__ sr_scale, const float* __restrict__ sr_bias,
    const float* __restrict__ w_lin, short* __restrict__ wlin_bf, short* __restrict__ xc_bf)
{
  __shared__ __align__(16) short xs[256 * 64];   // bf16 x halo: [c][dy*8+dx], rows h0-3..h0+4
  __shared__ __align__(16) float xrs[64 * 36];   // xr halo: [cr][ry*6+rx], rows h0-2..h0+3
  __shared__ __align__(16) float xcen[4 * 256];  // center x, pixel-major: [p][c]

  int blk = blockIdx.x;
  int b = blk >> 6, tile = blk & 63;
  int h0 = (tile >> 3) * 2, w0 = (tile & 7) * 2;
  int t = threadIdx.x;

  // --- w_lin fp32 -> bf16 (1024 elements per block, coalesced) ---
  {
    int base = blk * 1024 + t * 4;
    float4 v = *(const float4*)(w_lin + base);
    uint2 pk; pk.x = pk2bf(v.x, v.y); pk.y = pk2bf(v.z, v.w);
    *(uint2*)(wlin_bf + base) = pk;
  }

  // --- stage x halo (zero-padded) as bf16 ---
  const float* xb = x + b * 65536;
  #pragma unroll 4
  for (int i = 0; i < 64; ++i) {
    int idx = t + 256 * i;                 // 16384 = 256ch * 64pos
    int c = idx >> 6, pos = idx & 63;
    int gy = h0 - 3 + (pos >> 3), gx = w0 - 3 + (pos & 7);
    float v = 0.f;
    if (gy >= 0 && gy < 16 && gx >= 0 && gx < 16) v = xb[c * 256 + gy * 16 + gx];
    xs[idx] = (short)f2bf(v);
  }
  __syncthreads();

  // --- grouped 3x3 conv (channle_reduce): xr on 6x6 halo; zero OUTSIDE image ---
  for (int i = 0; i < 9; ++i) {
    int idx = t + 256 * i;                 // 2304 = 64ch * 36pos
    int cr = idx / 36, pos = idx - cr * 36;
    int ry = pos / 6, rx = pos - ry * 6;
    int gy = h0 - 2 + ry, gx = w0 - 2 + rx;
    float a = 0.f;
    if (gy >= 0 && gy < 16 && gx >= 0 && gx < 16) {
      a = b_cr[cr];
      #pragma unroll
      for (int ii = 0; ii < 4; ++ii) {
        const float* wp = w_cr + (cr * 4 + ii) * 9;
        const short* xp = xs + (cr * 4 + ii) * 64 + ry * 8 + rx;
        #pragma unroll
        for (int ky = 0; ky < 3; ++ky)
          #pragma unroll
          for (int kx = 0; kx < 3; ++kx)
            a += wp[ky * 3 + kx] * bf2f(xp[ky * 8 + kx]);
      }
    }
    xrs[idx] = a;
  }
  // --- center-pixel x vectors, pixel-major (for vectorized gate dot) ---
  for (int i = 0; i < 4; ++i) {
    int idx = t + 256 * i;                 // 1024 = 4pix * 256ch
    int pp = idx >> 8, c = idx & 255;
    xcen[idx] = bf2f(xs[c * 64 + ((pp >> 1) + 3) * 8 + (pp & 1) + 3]);
  }
  __syncthreads();

  // --- gate conv + BN + StarReLU; each thread: channel o, 2 pixels (ph, w0/w0+1)
  int o = t & 127, ph = t >> 7;
  float ga0 = 0.f, ga1 = 0.f;
  const float* wrow = w_gate + o * 256;
  const float* xc0 = xcen + ph * 512;
  const float* xc1 = xcen + ph * 512 + 256;
  #pragma unroll 8
  for (int ci = 0; ci < 256; ci += 4) {
    float4 wv = *(const float4*)(wrow + ci);
    float4 a0 = *(const float4*)(xc0 + ci);
    float4 a1 = *(const float4*)(xc1 + ci);
    ga0 += wv.x * a0.x + wv.y * a0.y + wv.z * a0.z + wv.w * a0.w;
    ga1 += wv.x * a1.x + wv.y * a1.y + wv.z * a1.z + wv.w * a1.w;
  }
  float inv = bn_gamma[o] * rsqrtf(bn_var[o] + BN_EPS);
  float ss = sr_scale[0], sb = sr_bias[0];
  float g0 = (ga0 + b_gate[o] - bn_mean[o]) * inv + bn_beta[o];
  float g1 = (ga1 + b_gate[o] - bn_mean[o]) * inv + bn_beta[o];
  g0 = fmaxf(g0, 0.f); g0 = ss * g0 * g0 + sb;
  g1 = fmaxf(g1, 0.f); g1 = ss * g1 * g1 + sb;

  // --- depthwise 3x3 (ch<64) / 5x5 (ch>=64) on xr halo ---
  float f0, f1;
  if (o < 64) {
    f0 = b_dw3[o]; f1 = b_dw3[o];
    const float* wp = w_dw3 + o * 9;
    const float* xp = xrs + o * 36;
    #pragma unroll
    for (int ky = 0; ky < 3; ++ky)
      #pragma unroll
      for (int kx = 0; kx < 3; ++kx) {
        float wv = wp[ky * 3 + kx];
        f0 += wv * xp[(ph + 1 + ky) * 6 + 1 + kx];
        f1 += wv * xp[(ph + 1 + ky) * 6 + 2 + kx];
      }
  } else {
    int oc = o - 64;
    f0 = b_dw7[oc]; f1 = b_dw7[oc];
    const float* wp = w_dw7 + oc * 25;
    const float* xp = xrs + oc * 36;
    #pragma unroll
    for (int ky = 0; ky < 5; ++ky)
      #pragma unroll
      for (int kx = 0; kx < 5; ++kx) {
        float wv = wp[ky * 5 + kx];
        f0 += wv * xp[(ph + ky) * 6 + kx];
        f1 += wv * xp[(ph + ky) * 6 + 1 + kx];
      }
  }
  int pix = (b * 16 + h0 + ph) * 16 + w0;
  xc_bf[pix * 128 + o]       = (short)f2bf(f0 * g0);
  xc_bf[(pix + 1) * 128 + o] = (short)f2bf(f1 * g1);
}

// =====================  K2: fused W-gen + dynamic conv  =====================
// grid 512 blocks (one per (b, f, g) 8x8 patch), 256 threads = 4 waves.
// LDS swizzle (16B-chunk xor) keeps W-gen scatter writes AND b128 frag reads
// at <=2-way bank conflicts (free per m136).
__global__ __launch_bounds__(256, 2) void k2_dynconv(
    const float* __restrict__ y, const float* __restrict__ b_lin,
    const short* __restrict__ wlin_bf, const short* __restrict__ xc_bf,
    float* __restrict__ out)
{
  __shared__ __align__(16) short Ylds[16384];  // Y^T: [pix n][ch k], swizzled, 32 KB
  __shared__ __align__(16) short Wlds[16384];  // W chunk: [e][cl 0..63], swizzled, 32 KB

  int blk = blockIdx.x;
  int b = blk >> 8, f = (blk >> 4) & 15, g = blk & 15;
  int tid = threadIdx.x;
  int wave = tid >> 6, lane = tid & 63;
  int quad = lane >> 4, l16 = lane & 15;

  // ---- stage Y patch (transposed to pixel-major, bf16) ----
  const float* yb = y + b * 4194304 + (f * 8) * 128 + g * 8;
  {
    int p = lane >> 3, q = lane & 7;           // lane <-> pixel
    #pragma unroll
    for (int j = 0; j < 16; ++j) {
      int c = wave * 64 + j * 4;               // wave owns 64 channels
      const float* ya = yb + c * 16384 + p * 128 + q;
      float v0 = ya[0], v1 = ya[16384], v2 = ya[32768], v3 = ya[49152];
      uint2 pk; pk.x = pk2bf(v0, v1); pk.y = pk2bf(v2, v3);
      int idx = lane * 256 + (((c >> 3) ^ (lane & 7)) << 3) + (c & 7);
      *(uint2*)&Ylds[idx] = pk;
    }
  }
  // ---- W-gen B-operand: xc vector of this pixel (constant all chunks) ----
  // B[k=quad*8+j][n=l16] = xc[n*16+k] for k<16, n<8; else 0
  short8 xfrag = {0, 0, 0, 0, 0, 0, 0, 0};
  if (quad < 2 && l16 < 8) {
    int pix = (b * 16 + f) * 16 + g;
    xfrag = *(const short8*)(xc_bf + pix * 128 + l16 * 16 + quad * 8);
  }
  __syncthreads();

  f32x4 acc[4][4];
  f32x4 zero4 = {0.f, 0.f, 0.f, 0.f};
  #pragma unroll
  for (int et = 0; et < 4; ++et)
    #pragma unroll
    for (int nt = 0; nt < 4; ++nt)
      acc[et][nt] = zero4;

  for (int cc = 0; cc < 4; ++cc) {           // 64-channel K-chunks
    // ---- W-gen: wave does 32 MFMA tiles (16 o-rows x 8 groups each) ----
    #pragma unroll 4
    for (int i = 0; i < 32; ++i) {
      int tt = wave * 32 + i;                // 128 tiles/chunk
      int e31 = tt >> 2, sub = tt & 3;
      int o0 = e31 * 256 + cc * 64 + sub * 16;
      short8 af = {0, 0, 0, 0, 0, 0, 0, 0};  // A[m=l16][k=quad*8+j]; k>=16 zero-pad
      if (quad < 2) af = *(const short8*)(wlin_bf + (o0 + l16) * 16 + quad * 8);
      f32x4 d = __builtin_amdgcn_mfma_f32_16x16x32_bf16(af, xfrag, zero4, 0, 0, 0);
      if (l16 < 8) {                         // D col = group n = l16
        float4 bv = *(const float4*)(b_lin + o0 + quad * 4);
        int e = l16 * 32 + e31;              // embed row
        int cl = sub * 16 + quad * 4;        // channel-within-chunk
        uint2 pk; pk.x = pk2bf(d[0] + bv.x, d[1] + bv.y);
        pk.y = pk2bf(d[2] + bv.z, d[3] + bv.w);
        int idx = e * 64 + ((((cl >> 3) ^ (e & 7) ^ (e >> 5))) << 3) + (cl & 7);
        *(uint2*)&Wlds[idx] = pk;
      }
    }
    __syncthreads();
    // ---- main matmul over this chunk: 2 K-steps x 16 MFMA tiles / wave ----
    #pragma unroll
    for (int ks = 0; ks < 2; ++ks) {
      short8 A[4], Bf[4];
      int mpart = ks * 4 + quad;             // cl>>3 of A-frag
      #pragma unroll
      for (int et = 0; et < 4; ++et) {
        int e = wave * 64 + et * 16 + l16;
        A[et] = *(const short8*)&Wlds[e * 64 + (((mpart ^ (e & 7) ^ (e >> 5))) << 3)];
      }
      int kc = (cc * 64 + ks * 32 + quad * 8) >> 3;
      #pragma unroll
      for (int nt = 0; nt < 4; ++nt) {
        int nn = nt * 16 + l16;
        Bf[nt] = *(const short8*)&Ylds[nn * 256 + (((kc ^ (nn & 7))) << 3)];
      }
      #pragma unroll
      for (int et = 0; et < 4; ++et)
        #pragma unroll
        for (int nt = 0; nt < 4; ++nt)
          acc[et][nt] = __builtin_amdgcn_mfma_f32_16x16x32_bf16(A[et], Bf[nt], acc[et][nt], 0, 0, 0);
    }
    __syncthreads();                          // next chunk's W-gen overwrites Wlds
  }

  // ---- epilogue: D row = e offset (quad*4+r), col = pixel (l16) ----
  float* ob = out + b * 4194304 + (f * 8) * 128 + g * 8;
  #pragma unroll
  for (int et = 0; et < 4; ++et) {
    int e0 = wave * 64 + et * 16 + quad * 4;
    #pragma unroll
    for (int nt = 0; nt < 4; ++nt) {
      int pix = nt * 16 + l16;
      float* oa = ob + (pix >> 3) * 128 + (pix & 7);
      #pragma unroll
      for (int r = 0; r < 4; ++r)
        oa[(e0 + r) * 16384] = acc[et][nt][r];
    }
  }
}

// ============================  launcher  ============================
extern "C" void kernel_launch(void* const* d_in, const int* in_sizes, int n_in,
                              void* d_out, int out_size, void* d_ws, size_t ws_size,
                              hipStream_t stream) {
  const float* x        = (const float*)d_in[0];
  const float* y        = (const float*)d_in[1];
  const float* w_cr     = (const float*)d_in[2];
  const float* b_cr     = (const float*)d_in[3];
  const float* w_dw3    = (const float*)d_in[4];
  const float* b_dw3    = (const float*)d_in[5];
  const float* w_dw7    = (const float*)d_in[6];
  const float* b_dw7    = (const float*)d_in[7];
  const float* w_gate   = (const float*)d_in[8];
  const float* b_gate   = (const float*)d_in[9];
  const float* bn_gamma = (const float*)d_in[10];
  const float* bn_beta  = (const float*)d_in[11];
  const float* bn_mean  = (const float*)d_in[12];
  const float* bn_var   = (const float*)d_in[13];
  const float* sr_scale = (const float*)d_in[14];
  const float* sr_bias  = (const float*)d_in[15];
  const float* w_lin    = (const float*)d_in[16];
  const float* b_lin    = (const float*)d_in[17];
  float* out = (float*)d_out;

  // workspace: xc_bf16 [2*16*16][128] (128 KB) | w_lin bf16 [8192*16] (256 KB)
  short* xc_bf   = (short*)d_ws;
  short* wlin_bf = (short*)((char*)d_ws + 131072);

  hipLaunchKernelGGL(k1_features, dim3(128), dim3(256), 0, stream,
                     x, w_cr, b_cr, w_dw3, b_dw3, w_dw7, b_dw7, w_gate, b_gate,
                     bn_gamma, bn_beta, bn_mean, bn_var, sr_scale, sr_bias,
                     w_lin, wlin_bf, xc_bf);
  hipLaunchKernelGGL(k2_dynconv, dim3(512), dim3(256), 0, stream,
                     y, b_lin, wlin_bf, xc_bf, out);
}